// Round 3
// baseline (1907.899 us; speedup 1.0000x reference)
//
#include <hip/hip_runtime.h>
#include <math.h>

// ---------------- problem constants ----------------
#define BATCH 32768
#define HID   512
#define NOBJ  5
#define TM    128           // batch rows per block (MFMA path), 512 threads

typedef __attribute__((ext_vector_type(8))) short bf16x8;
typedef __attribute__((ext_vector_type(4))) float f32x4;

__device__ __constant__ int d_OIDS[5][12] = {
  {0,1,2,3, 10,11,12,13,14,18,22,26},
  {0,4,5,6, 10,14,15,16,17,19,23,27},
  {1,4,7,8, 11,15,18,19,20,21,24,28},
  {2,5,7,9, 12,16,20,22,23,24,25,29},
  {3,6,8,9, 13,17,21,25,26,27,28,29}
};

// ---------------- bf16 weight workspace (ushort offsets) ----------------
#define UO_EW0   0                       // [512][64]  (K padded 44->64)
#define UO_EW1   (UO_EW0 + 512*64)       // [512][512]
#define UO_HEADS (UO_EW1 + 512*512)      // [32][512]: rows 0-8 Wm, 16-24 Wv, rest 0
#define UO_DW0   (UO_HEADS + 32*512)     // [512][64]  (K padded 41->64)
#define UO_DW1   (UO_DW0 + 512*64)       // [512][512]
#define UO_DW2   (UO_DW1 + 512*512)      // [16][512]: rows 0-11 dec_W2, rest 0
#define UO_TOTAL (UO_DW2 + 16*512)       // 614400 ushorts = 1.23 MB

// ---------------- output layout (floats) ----------------
#define OUT_MEANS (BATCH*30)
#define OUT_LV    (OUT_MEANS + NOBJ*BATCH*9)
#define OUT_Z     (OUT_LV    + NOBJ*BATCH*9)

// round-to-nearest-even f32 -> bf16 bits
__device__ __forceinline__ unsigned short f2b(float x) {
  unsigned int u = __builtin_bit_cast(unsigned int, x);
  u += 0x7FFFu + ((u >> 16) & 1u);
  return (unsigned short)(u >> 16);
}

// ---------------- prep: convert/pad weights into ws (bf16) ----------------
__global__ void __launch_bounds__(256)
prep_bf16(const float* __restrict__ eW0, const float* __restrict__ eW1,
          const float* __restrict__ Wm,  const float* __restrict__ Wv,
          const float* __restrict__ dW0, const float* __restrict__ dW1,
          const float* __restrict__ dW2, unsigned short* __restrict__ ws)
{
  for (int i = blockIdx.x*blockDim.x + threadIdx.x; i < UO_TOTAL; i += gridDim.x*blockDim.x) {
    float v = 0.f; int j;
    if (i < UO_EW1) {                       // [512][64] <- eW0 [512][44]
      j = i - UO_EW0; int h = j >> 6, k = j & 63;
      if (k < 44) v = eW0[h*44 + k];
    } else if (i < UO_HEADS) {              // [512][512] <- eW1
      j = i - UO_EW1; v = eW1[j];
    } else if (i < UO_DW0) {                // [32][512] heads
      j = i - UO_HEADS; int r = j >> 9, k = j & 511;
      if (r < 9)                  v = Wm[r*512 + k];
      else if (r >= 16 && r < 25) v = Wv[(r-16)*512 + k];
    } else if (i < UO_DW1) {                // [512][64] <- dW0 [512][41]
      j = i - UO_DW0; int h = j >> 6, k = j & 63;
      if (k < 41) v = dW0[h*41 + k];
    } else if (i < UO_DW2) {                // [512][512] <- dW1
      j = i - UO_DW1; v = dW1[j];
    } else {                                // [16][512] <- dW2 [12][512]
      j = i - UO_DW2; int r = j >> 9, k = j & 511;
      if (r < 12) v = dW2[r*512 + k];
    }
    ws[i] = f2b(v);
  }
}

// One dense layer via MFMA: out[128][512] = relu(in[128][K] * W^T + bias)
// 8 waves as 2(M) x 4(N): wave (wm,wn) covers rows [wm*64,+64) x cols [wn*128,+128).
// Software pipeline: even/odd register double-buffer for A (LDS) and B (global).
// In-place (sIn==sOut) safe: all K-loop reads complete before mid-barrier.
template<int KT, int ROWW>   // K = KT*32
__device__ __forceinline__ void layer_mfma(const unsigned short* sIn,
                                           const unsigned short* __restrict__ Wb,
                                           const float* __restrict__ bias,
                                           unsigned short* sOut,
                                           int wm, int wn, int lane)
{
  const int lcol = lane & 15;
  const int lk   = (lane >> 4) * 8;
  const int colbase = wn * 128;
  const int rowbase = wm * 64;

  f32x4 acc[4][8];
  #pragma unroll
  for (int n = 0; n < 8; ++n) {
    const float bv = bias[colbase + n*16 + lcol];
    #pragma unroll
    for (int m = 0; m < 4; ++m) acc[m][n] = (f32x4){bv, bv, bv, bv};
  }

  bf16x8 a0[4], a1[4], b0[8], b1[8];
  #pragma unroll
  for (int m = 0; m < 4; ++m) {
    const int row = rowbase + m*16 + lcol;
    a0[m] = *(const bf16x8*)&sIn[row*ROWW + (lk ^ ((row & 7) << 3))];
  }
  #pragma unroll
  for (int n = 0; n < 8; ++n)
    b0[n] = *(const bf16x8*)&Wb[(colbase + n*16 + lcol)*(KT*32) + lk];

  #pragma unroll
  for (int kt = 0; kt < KT; kt += 2) {
    if (kt + 1 < KT) {                     // prefetch kt+1 into odd buffers
      const int k1 = (kt+1)*32 + lk;
      #pragma unroll
      for (int n = 0; n < 8; ++n)
        b1[n] = *(const bf16x8*)&Wb[(colbase + n*16 + lcol)*(KT*32) + k1];
      #pragma unroll
      for (int m = 0; m < 4; ++m) {
        const int row = rowbase + m*16 + lcol;
        a1[m] = *(const bf16x8*)&sIn[row*ROWW + (k1 ^ ((row & 7) << 3))];
      }
    }
    #pragma unroll
    for (int n = 0; n < 8; ++n)
      #pragma unroll
      for (int m = 0; m < 4; ++m)
        acc[m][n] = __builtin_amdgcn_mfma_f32_16x16x32_bf16(a0[m], b0[n], acc[m][n], 0, 0, 0);
    if (kt + 2 < KT) {                     // prefetch kt+2 into even buffers
      const int k2 = (kt+2)*32 + lk;
      #pragma unroll
      for (int n = 0; n < 8; ++n)
        b0[n] = *(const bf16x8*)&Wb[(colbase + n*16 + lcol)*(KT*32) + k2];
      #pragma unroll
      for (int m = 0; m < 4; ++m) {
        const int row = rowbase + m*16 + lcol;
        a0[m] = *(const bf16x8*)&sIn[row*ROWW + (k2 ^ ((row & 7) << 3))];
      }
    }
    if (kt + 1 < KT) {
      #pragma unroll
      for (int n = 0; n < 8; ++n)
        #pragma unroll
        for (int m = 0; m < 4; ++m)
          acc[m][n] = __builtin_amdgcn_mfma_f32_16x16x32_bf16(a1[m], b1[n], acc[m][n], 0, 0, 0);
    }
  }

  __syncthreads();   // all reads of sIn done before (possibly aliased) writes
  const int rbase = (lane >> 4) * 4;
  #pragma unroll
  for (int m = 0; m < 4; ++m)
    #pragma unroll
    for (int n = 0; n < 8; ++n) {
      const int col = colbase + n*16 + lcol;
      #pragma unroll
      for (int r = 0; r < 4; ++r) {
        const int row = rowbase + m*16 + rbase + r;
        sOut[row*512 + (col ^ ((row & 7) << 3))] = f2b(fmaxf(acc[m][n][r], 0.f));
      }
    }
  __syncthreads();
}

__global__ void __launch_bounds__(512, 2)
vae_mfma(const float* __restrict__ initial_c, const float* __restrict__ initial_s,
         const float* __restrict__ current_c, const float* __restrict__ eps,
         const float* __restrict__ enc_b0, const float* __restrict__ enc_b1,
         const float* __restrict__ bm, const float* __restrict__ bv,
         const float* __restrict__ dec_b0, const float* __restrict__ dec_b1,
         const float* __restrict__ dec_b2, const unsigned short* __restrict__ ws,
         float* __restrict__ out)
{
  __shared__ __align__(16) unsigned short s_act[TM*512];  // 128 KB activations (in-place)
  __shared__ __align__(16) unsigned short s_in[TM*64];    // 16 KB enc/dec input (K pad 64)
  __shared__ float s_rec[TM*30];                          // 15 KB scatter accumulator
  // total 159 KB -> 1 block/CU, 8 waves

  const int t = threadIdx.x;
  const int wave = t >> 6, lane = t & 63;
  const int wm = wave >> 2, wn = wave & 3;
  const int lcol = lane & 15, lk = (lane >> 4) * 8, rbase = (lane >> 4) * 4;
  const int bbase = blockIdx.x * TM;

  for (int s = t; s < TM*30; s += 512) s_rec[s] = 0.f;

  for (int o = 0; o < NOBJ; ++o) {
    __syncthreads();

    // ---- encoder input [128][64]: [oh 0-4 | s 5-19 | gi 20-31 | gc 32-43 | 0] ----
    for (int s = t; s < TM*64; s += 512) {
      const int row = s >> 6, col = s & 63;
      float v = 0.f;
      if (col < 5)       v = (col == o) ? 1.f : 0.f;
      else if (col < 20) v = initial_s[(bbase+row)*15 + col - 5];
      else if (col < 32) v = initial_c[(bbase+row)*30 + d_OIDS[o][col-20]];
      else if (col < 44) v = current_c[(bbase+row)*30 + d_OIDS[o][col-32]];
      s_in[row*64 + (col ^ ((row & 7) << 3))] = f2b(v);
    }
    __syncthreads();

    layer_mfma<2, 64>  (s_in,  ws + UO_EW0, enc_b0, s_act, wm, wn, lane);  // h1
    layer_mfma<16, 512>(s_act, ws + UO_EW1, enc_b1, s_act, wm, wn, lane);  // h2 in-place

    // ---- heads: means / log_var / z (wave owns M-tile `wave`: rows wave*16..+15) ----
    {
      // decoder input (non-z cols): [oh 0-4 | z 5-13 | s 14-28 | gi 29-40 | 0]
      for (int s = t; s < TM*64; s += 512) {
        const int row = s >> 6, col = s & 63;
        if (col >= 5 && col < 14) continue;
        float v = 0.f;
        if (col < 5)       v = (col == o) ? 1.f : 0.f;
        else if (col < 29) v = initial_s[(bbase+row)*15 + col - 14];
        else if (col < 41) v = initial_c[(bbase+row)*30 + d_OIDS[o][col-29]];
        s_in[row*64 + (col ^ ((row & 7) << 3))] = f2b(v);
      }
      const float bmv = (lcol < 9) ? bm[lcol] : 0.f;
      const float bvv = (lcol < 9) ? bv[lcol] : 0.f;
      f32x4 am = (f32x4){bmv, bmv, bmv, bmv};
      f32x4 av = (f32x4){bvv, bvv, bvv, bvv};
      const unsigned short* hw = ws + UO_HEADS;
      const int hrow = wave*16 + lcol;
      #pragma unroll
      for (int kt = 0; kt < 16; ++kt) {
        const int k0 = kt*32 + lk;
        bf16x8 a  = *(const bf16x8*)&s_act[hrow*512 + (k0 ^ ((hrow & 7) << 3))];
        bf16x8 bM = *(const bf16x8*)&hw[lcol*512 + k0];
        bf16x8 bV = *(const bf16x8*)&hw[(16 + lcol)*512 + k0];
        am = __builtin_amdgcn_mfma_f32_16x16x32_bf16(a, bM, am, 0, 0, 0);
        av = __builtin_amdgcn_mfma_f32_16x16x32_bf16(a, bV, av, 0, 0, 0);
      }
      __syncthreads();   // all head reads of s_act done -> stage area free
      float* stage = (float*)s_act;        // [3][128][9] f32 = 13.8 KB
      if (lcol < 9) {
        #pragma unroll
        for (int r = 0; r < 4; ++r) {
          const int row = wave*16 + rbase + r;
          const int gid = (o*BATCH + bbase + row)*9 + lcol;
          const float m_ = am[r], v_ = av[r];
          const float zz = fmaf(eps[gid], expf(0.5f*v_), m_);
          stage[        row*9 + lcol] = m_;
          stage[1152 +  row*9 + lcol] = v_;
          stage[2304 +  row*9 + lcol] = zz;
          s_in[row*64 + ((5 + lcol) ^ ((row & 7) << 3))] = f2b(zz);
        }
      }
      __syncthreads();
      // coalesced head-output writes (contiguous 4.6 KB each)
      const int ob_m = OUT_MEANS + (o*BATCH + bbase)*9;
      const int ob_v = OUT_LV    + (o*BATCH + bbase)*9;
      const int ob_z = OUT_Z     + (o*BATCH + bbase)*9;
      for (int i = t; i < TM*9; i += 512) {
        out[ob_m + i] = stage[i];
        out[ob_v + i] = stage[1152 + i];
        out[ob_z + i] = stage[2304 + i];
      }
      // no extra sync needed: dec0's internal mid-barrier orders s_act overwrite
    }

    layer_mfma<2, 64>  (s_in,  ws + UO_DW0, dec_b0, s_act, wm, wn, lane);  // g1
    layer_mfma<16, 512>(s_act, ws + UO_DW1, dec_b1, s_act, wm, wn, lane);  // g2 in-place

    // ---- dec head: sigmoid + scatter into s_rec (wave owns M-tile `wave`) ----
    {
      const float b2 = (lcol < 12) ? dec_b2[lcol] : 0.f;
      f32x4 acc = (f32x4){b2, b2, b2, b2};
      const unsigned short* w2 = ws + UO_DW2;
      const int hrow = wave*16 + lcol;
      #pragma unroll
      for (int kt = 0; kt < 16; ++kt) {
        const int k0 = kt*32 + lk;
        bf16x8 a = *(const bf16x8*)&s_act[hrow*512 + (k0 ^ ((hrow & 7) << 3))];
        bf16x8 b = *(const bf16x8*)&w2[lcol*512 + k0];
        acc = __builtin_amdgcn_mfma_f32_16x16x32_bf16(a, b, acc, 0, 0, 0);
      }
      if (lcol < 12) {
        const int c30 = d_OIDS[o][lcol];
        #pragma unroll
        for (int r = 0; r < 4; ++r) {
          const int row = wave*16 + rbase + r;
          s_rec[row*30 + c30] += 1.f / (1.f + expf(-acc[r]));
        }
      }
    }
  }

  __syncthreads();
  for (int s = t; s < TM*30; s += 512)
    out[(bbase + s/30)*30 + s%30] = s_rec[s];
}

// ---------------- fallback (ws too small): correct but slow fp32 ----------------
__global__ void __launch_bounds__(256)
vae_naive(const float* __restrict__ initial_c, const float* __restrict__ initial_s,
          const float* __restrict__ current_c, const float* __restrict__ eps,
          const float* eW0, const float* eb0, const float* eW1, const float* eb1,
          const float* Wm, const float* bm, const float* Wv, const float* bv,
          const float* dW0, const float* db0, const float* dW1, const float* db1,
          const float* dW2, const float* db2, float* out)
{
  __shared__ float xs[44], ds[41], h1[HID], h2[HID], rec[30];
  const int b = blockIdx.x, t = threadIdx.x;
  if (t < 30) rec[t] = 0.f;
  for (int o = 0; o < NOBJ; ++o) {
    __syncthreads();
    if (t < 44) {
      float v;
      if      (t < 5)  v = (t == o) ? 1.f : 0.f;
      else if (t < 20) v = initial_s[b*15 + (t-5)];
      else if (t < 32) v = initial_c[b*30 + d_OIDS[o][t-20]];
      else             v = current_c[b*30 + d_OIDS[o][t-32]];
      xs[t] = v;
    }
    __syncthreads();
    for (int h = t; h < HID; h += 256) {
      float a = eb0[h];
      for (int k = 0; k < 44; ++k) a = fmaf(xs[k], eW0[h*44+k], a);
      h1[h] = fmaxf(a, 0.f);
    }
    __syncthreads();
    for (int h = t; h < HID; h += 256) {
      float a = eb1[h];
      for (int k = 0; k < HID; ++k) a = fmaf(h1[k], eW1[h*512+k], a);
      h2[h] = fmaxf(a, 0.f);
    }
    __syncthreads();
    if (t < 9) {
      float am = bm[t], av = bv[t];
      for (int k = 0; k < HID; ++k) { am = fmaf(h2[k], Wm[t*512+k], am); av = fmaf(h2[k], Wv[t*512+k], av); }
      const int gid = (o*BATCH + b)*9 + t;
      out[OUT_MEANS + gid] = am;
      out[OUT_LV    + gid] = av;
      const float zz = fmaf(eps[gid], expf(0.5f*av), am);
      out[OUT_Z     + gid] = zz;
      ds[5+t] = zz;
    }
    if (t < 41 && (t < 5 || t >= 14)) {
      float v;
      if      (t < 5)  v = (t == o) ? 1.f : 0.f;
      else if (t < 29) v = initial_s[b*15 + (t-14)];
      else             v = initial_c[b*30 + d_OIDS[o][t-29]];
      ds[t] = v;
    }
    __syncthreads();
    for (int h = t; h < HID; h += 256) {
      float a = db0[h];
      for (int k = 0; k < 41; ++k) a = fmaf(ds[k], dW0[h*41+k], a);
      h1[h] = fmaxf(a, 0.f);
    }
    __syncthreads();
    for (int h = t; h < HID; h += 256) {
      float a = db1[h];
      for (int k = 0; k < HID; ++k) a = fmaf(h1[k], dW1[h*512+k], a);
      h2[h] = fmaxf(a, 0.f);
    }
    __syncthreads();
    if (t < 12) {
      float a = db2[t];
      for (int k = 0; k < HID; ++k) a = fmaf(h2[k], dW2[t*512+k], a);
      rec[d_OIDS[o][t]] += 1.f / (1.f + expf(-a));
    }
  }
  __syncthreads();
  if (t < 30) out[b*30+t] = rec[t];
}

extern "C" void kernel_launch(void* const* d_in, const int* in_sizes, int n_in,
                              void* d_out, int out_size, void* d_ws, size_t ws_size,
                              hipStream_t stream)
{
  const float* initial_c = (const float*)d_in[0];
  const float* initial_s = (const float*)d_in[1];
  const float* current_c = (const float*)d_in[2];
  const float* eps       = (const float*)d_in[3];
  const float* eW0 = (const float*)d_in[4];
  const float* eb0 = (const float*)d_in[5];
  const float* eW1 = (const float*)d_in[6];
  const float* eb1 = (const float*)d_in[7];
  const float* Wm  = (const float*)d_in[8];
  const float* bm  = (const float*)d_in[9];
  const float* Wv  = (const float*)d_in[10];
  const float* bv  = (const float*)d_in[11];
  const float* dW0 = (const float*)d_in[12];
  const float* db0 = (const float*)d_in[13];
  const float* dW1 = (const float*)d_in[14];
  const float* db1 = (const float*)d_in[15];
  const float* dW2 = (const float*)d_in[16];
  const float* db2 = (const float*)d_in[17];
  float* out = (float*)d_out;

  if (ws_size >= (size_t)UO_TOTAL * sizeof(unsigned short)) {
    unsigned short* ws = (unsigned short*)d_ws;
    prep_bf16<<<1024, 256, 0, stream>>>(eW0, eW1, Wm, Wv, dW0, dW1, dW2, ws);
    vae_mfma<<<BATCH/TM, 512, 0, stream>>>(initial_c, initial_s, current_c, eps,
                                           eb0, eb1, bm, bv, db0, db1, db2, ws, out);
  } else {
    vae_naive<<<BATCH, 256, 0, stream>>>(initial_c, initial_s, current_c, eps,
                                         eW0, eb0, eW1, eb1, Wm, bm, Wv, bv,
                                         dW0, db0, dW1, db1, dW2, db2, out);
  }
}

// Round 4
// 870.640 us; speedup vs baseline: 2.1914x; 2.1914x over previous
//
#include <hip/hip_runtime.h>
#include <math.h>

// ---------------- problem constants ----------------
#define BATCH 32768
#define HID   512
#define NOBJ  5
#define TM    128           // batch rows per block (MFMA path), 512 threads

typedef __attribute__((ext_vector_type(8))) short bf16x8;
typedef __attribute__((ext_vector_type(4))) float f32x4;

__device__ __constant__ int d_OIDS[5][12] = {
  {0,1,2,3, 10,11,12,13,14,18,22,26},
  {0,4,5,6, 10,14,15,16,17,19,23,27},
  {1,4,7,8, 11,15,18,19,20,21,24,28},
  {2,5,7,9, 12,16,20,22,23,24,25,29},
  {3,6,8,9, 13,17,21,25,26,27,28,29}
};

// ---------------- bf16 weight workspace (ushort offsets) ----------------
#define UO_EW0   0                       // [512][64]  (K padded 44->64)
#define UO_EW1   (UO_EW0 + 512*64)       // [512][512]
#define UO_HEADS (UO_EW1 + 512*512)      // [32][512]: rows 0-8 Wm, 16-24 Wv, rest 0
#define UO_DW0   (UO_HEADS + 32*512)     // [512][64]  (K padded 41->64)
#define UO_DW1   (UO_DW0 + 512*64)       // [512][512]
#define UO_DW2   (UO_DW1 + 512*512)      // [16][512]: rows 0-11 dec_W2, rest 0
#define UO_TOTAL (UO_DW2 + 16*512)       // 614400 ushorts = 1.23 MB

// ---------------- output layout (floats) ----------------
#define OUT_MEANS (BATCH*30)
#define OUT_LV    (OUT_MEANS + NOBJ*BATCH*9)
#define OUT_Z     (OUT_LV    + NOBJ*BATCH*9)

// round-to-nearest-even f32 -> bf16 bits
__device__ __forceinline__ unsigned short f2b(float x) {
  unsigned int u = __builtin_bit_cast(unsigned int, x);
  u += 0x7FFFu + ((u >> 16) & 1u);
  return (unsigned short)(u >> 16);
}

// ---------------- prep: convert/pad weights into ws (bf16) ----------------
__global__ void __launch_bounds__(256)
prep_bf16(const float* __restrict__ eW0, const float* __restrict__ eW1,
          const float* __restrict__ Wm,  const float* __restrict__ Wv,
          const float* __restrict__ dW0, const float* __restrict__ dW1,
          const float* __restrict__ dW2, unsigned short* __restrict__ ws)
{
  for (int i = blockIdx.x*blockDim.x + threadIdx.x; i < UO_TOTAL; i += gridDim.x*blockDim.x) {
    float v = 0.f; int j;
    if (i < UO_EW1) {                       // [512][64] <- eW0 [512][44]
      j = i - UO_EW0; int h = j >> 6, k = j & 63;
      if (k < 44) v = eW0[h*44 + k];
    } else if (i < UO_HEADS) {              // [512][512] <- eW1
      j = i - UO_EW1; v = eW1[j];
    } else if (i < UO_DW0) {                // [32][512] heads
      j = i - UO_HEADS; int r = j >> 9, k = j & 511;
      if (r < 9)                  v = Wm[r*512 + k];
      else if (r >= 16 && r < 25) v = Wv[(r-16)*512 + k];
    } else if (i < UO_DW1) {                // [512][64] <- dW0 [512][41]
      j = i - UO_DW0; int h = j >> 6, k = j & 63;
      if (k < 41) v = dW0[h*41 + k];
    } else if (i < UO_DW2) {                // [512][512] <- dW1
      j = i - UO_DW1; v = dW1[j];
    } else {                                // [16][512] <- dW2 [12][512]
      j = i - UO_DW2; int r = j >> 9, k = j & 511;
      if (r < 12) v = dW2[r*512 + k];
    }
    ws[i] = f2b(v);
  }
}

// One dense layer via MFMA: out[128][512] = relu(in[128][K] * W^T + bias)
// 8 waves, 1M x 8N: wave covers ALL 128 rows x cols [wave*64, wave*64+64).
// Each wave reads a DISTINCT 64-row weight panel (no duplication).
// K-loop: #pragma unroll 1 -> small live set (no spills); TLP (2 waves/SIMD)
// hides latency. In-place (sIn==sOut) safe: reads complete before mid-barrier.
template<int KT, int ROWW>   // K = KT*32
__device__ __forceinline__ void layer_mfma(const unsigned short* sIn,
                                           const unsigned short* __restrict__ Wb,
                                           const float* __restrict__ bias,
                                           unsigned short* sOut,
                                           int wave, int lane)
{
  const int lcol = lane & 15;
  const int lk   = (lane >> 4) * 8;
  const int colbase = wave * 64;

  f32x4 acc[8][4];
  #pragma unroll
  for (int n = 0; n < 4; ++n) {
    const float bv = bias[colbase + n*16 + lcol];
    #pragma unroll
    for (int m = 0; m < 8; ++m) acc[m][n] = (f32x4){bv, bv, bv, bv};
  }
  const unsigned short* wp0 = Wb + (colbase +  0 + lcol)*(KT*32) + lk;
  const unsigned short* wp1 = Wb + (colbase + 16 + lcol)*(KT*32) + lk;
  const unsigned short* wp2 = Wb + (colbase + 32 + lcol)*(KT*32) + lk;
  const unsigned short* wp3 = Wb + (colbase + 48 + lcol)*(KT*32) + lk;

  #pragma unroll 1
  for (int kt = 0; kt < KT; ++kt) {
    const int k0 = kt*32 + lk;
    bf16x8 b[4], a[8];
    b[0] = *(const bf16x8*)(wp0 + kt*32);
    b[1] = *(const bf16x8*)(wp1 + kt*32);
    b[2] = *(const bf16x8*)(wp2 + kt*32);
    b[3] = *(const bf16x8*)(wp3 + kt*32);
    #pragma unroll
    for (int m = 0; m < 8; ++m) {
      const int row = m*16 + lcol;
      a[m] = *(const bf16x8*)&sIn[row*ROWW + (k0 ^ ((row & 7) << 3))];
    }
    #pragma unroll
    for (int n = 0; n < 4; ++n)
      #pragma unroll
      for (int m = 0; m < 8; ++m)
        acc[m][n] = __builtin_amdgcn_mfma_f32_16x16x32_bf16(a[m], b[n], acc[m][n], 0, 0, 0);
  }

  __syncthreads();   // all reads of sIn done before (possibly aliased) writes
  const int rbase = (lane >> 4) * 4;
  #pragma unroll
  for (int m = 0; m < 8; ++m)
    #pragma unroll
    for (int n = 0; n < 4; ++n) {
      const int col = colbase + n*16 + lcol;
      #pragma unroll
      for (int r = 0; r < 4; ++r) {
        const int row = m*16 + rbase + r;
        sOut[row*512 + (col ^ ((row & 7) << 3))] = f2b(fmaxf(acc[m][n][r], 0.f));
      }
    }
  __syncthreads();
}

__global__ void __launch_bounds__(512, 2)
vae_mfma(const float* __restrict__ initial_c, const float* __restrict__ initial_s,
         const float* __restrict__ current_c, const float* __restrict__ eps,
         const float* __restrict__ enc_b0, const float* __restrict__ enc_b1,
         const float* __restrict__ bm, const float* __restrict__ bv,
         const float* __restrict__ dec_b0, const float* __restrict__ dec_b1,
         const float* __restrict__ dec_b2, const unsigned short* __restrict__ ws,
         float* __restrict__ out)
{
  __shared__ __align__(16) unsigned short s_act[TM*512];  // 128 KB activations (in-place)
  __shared__ __align__(16) unsigned short s_in[TM*64];    // 16 KB enc/dec input (K pad 64)
  __shared__ float s_rec[TM*30];                          // 15 KB scatter accumulator
  // total 159 KB -> 1 block/CU, 8 waves (2 waves/SIMD)

  const int t = threadIdx.x;
  const int wave = t >> 6, lane = t & 63;
  const int lcol = lane & 15, lk = (lane >> 4) * 8, rbase = (lane >> 4) * 4;
  const int bbase = blockIdx.x * TM;

  for (int s = t; s < TM*30; s += 512) s_rec[s] = 0.f;

  for (int o = 0; o < NOBJ; ++o) {
    __syncthreads();

    // ---- encoder input [128][64]: [oh 0-4 | s 5-19 | gi 20-31 | gc 32-43 | 0] ----
    for (int s = t; s < TM*64; s += 512) {
      const int row = s >> 6, col = s & 63;
      float v = 0.f;
      if (col < 5)       v = (col == o) ? 1.f : 0.f;
      else if (col < 20) v = initial_s[(bbase+row)*15 + col - 5];
      else if (col < 32) v = initial_c[(bbase+row)*30 + d_OIDS[o][col-20]];
      else if (col < 44) v = current_c[(bbase+row)*30 + d_OIDS[o][col-32]];
      s_in[row*64 + (col ^ ((row & 7) << 3))] = f2b(v);
    }
    __syncthreads();

    layer_mfma<2, 64>  (s_in,  ws + UO_EW0, enc_b0, s_act, wave, lane);  // h1
    layer_mfma<16, 512>(s_act, ws + UO_EW1, enc_b1, s_act, wave, lane);  // h2 in-place

    // ---- heads: means / log_var / z (wave owns rows wave*16..+15) ----
    {
      // decoder input (non-z cols): [oh 0-4 | z 5-13 | s 14-28 | gi 29-40 | 0]
      for (int s = t; s < TM*64; s += 512) {
        const int row = s >> 6, col = s & 63;
        if (col >= 5 && col < 14) continue;
        float v = 0.f;
        if (col < 5)       v = (col == o) ? 1.f : 0.f;
        else if (col < 29) v = initial_s[(bbase+row)*15 + col - 14];
        else if (col < 41) v = initial_c[(bbase+row)*30 + d_OIDS[o][col-29]];
        s_in[row*64 + (col ^ ((row & 7) << 3))] = f2b(v);
      }
      const float bmv = (lcol < 9) ? bm[lcol] : 0.f;
      const float bvv = (lcol < 9) ? bv[lcol] : 0.f;
      f32x4 am = (f32x4){bmv, bmv, bmv, bmv};
      f32x4 av = (f32x4){bvv, bvv, bvv, bvv};
      const unsigned short* hw = ws + UO_HEADS;
      const int hrow = wave*16 + lcol;
      const unsigned short* hpM = hw + lcol*512 + lk;
      const unsigned short* hpV = hw + (16 + lcol)*512 + lk;
      #pragma unroll 1
      for (int kt = 0; kt < 16; ++kt) {
        const int k0 = kt*32 + lk;
        bf16x8 a  = *(const bf16x8*)&s_act[hrow*512 + (k0 ^ ((hrow & 7) << 3))];
        bf16x8 bM = *(const bf16x8*)(hpM + kt*32);
        bf16x8 bV = *(const bf16x8*)(hpV + kt*32);
        am = __builtin_amdgcn_mfma_f32_16x16x32_bf16(a, bM, am, 0, 0, 0);
        av = __builtin_amdgcn_mfma_f32_16x16x32_bf16(a, bV, av, 0, 0, 0);
      }
      __syncthreads();   // all head reads of s_act done -> stage area free
      float* stage = (float*)s_act;        // [3][128][9] f32 = 13.8 KB
      if (lcol < 9) {
        #pragma unroll
        for (int r = 0; r < 4; ++r) {
          const int row = wave*16 + rbase + r;
          const int gid = (o*BATCH + bbase + row)*9 + lcol;
          const float m_ = am[r], v_ = av[r];
          const float zz = fmaf(eps[gid], expf(0.5f*v_), m_);
          stage[        row*9 + lcol] = m_;
          stage[1152 +  row*9 + lcol] = v_;
          stage[2304 +  row*9 + lcol] = zz;
          s_in[row*64 + ((5 + lcol) ^ ((row & 7) << 3))] = f2b(zz);
        }
      }
      __syncthreads();
      // coalesced nontemporal head-output writes (no L2 pollution)
      const int ob_m = OUT_MEANS + (o*BATCH + bbase)*9;
      const int ob_v = OUT_LV    + (o*BATCH + bbase)*9;
      const int ob_z = OUT_Z     + (o*BATCH + bbase)*9;
      for (int i = t; i < TM*9; i += 512) {
        __builtin_nontemporal_store(stage[i],        &out[ob_m + i]);
        __builtin_nontemporal_store(stage[1152 + i], &out[ob_v + i]);
        __builtin_nontemporal_store(stage[2304 + i], &out[ob_z + i]);
      }
      // no extra sync needed: dec0's internal mid-barrier orders s_act overwrite
    }

    layer_mfma<2, 64>  (s_in,  ws + UO_DW0, dec_b0, s_act, wave, lane);  // g1
    layer_mfma<16, 512>(s_act, ws + UO_DW1, dec_b1, s_act, wave, lane);  // g2 in-place

    // ---- dec head: sigmoid + scatter into s_rec (wave owns rows wave*16..+15) ----
    {
      const float b2 = (lcol < 12) ? dec_b2[lcol] : 0.f;
      f32x4 acc = (f32x4){b2, b2, b2, b2};
      const unsigned short* w2 = ws + UO_DW2;
      const int hrow = wave*16 + lcol;
      const unsigned short* wp = w2 + lcol*512 + lk;
      #pragma unroll 1
      for (int kt = 0; kt < 16; ++kt) {
        const int k0 = kt*32 + lk;
        bf16x8 a = *(const bf16x8*)&s_act[hrow*512 + (k0 ^ ((hrow & 7) << 3))];
        bf16x8 b = *(const bf16x8*)(wp + kt*32);
        acc = __builtin_amdgcn_mfma_f32_16x16x32_bf16(a, b, acc, 0, 0, 0);
      }
      if (lcol < 12) {
        const int c30 = d_OIDS[o][lcol];
        #pragma unroll
        for (int r = 0; r < 4; ++r) {
          const int row = wave*16 + rbase + r;
          s_rec[row*30 + c30] += 1.f / (1.f + expf(-acc[r]));
        }
      }
    }
  }

  __syncthreads();
  for (int s = t; s < TM*30; s += 512)
    __builtin_nontemporal_store(s_rec[s], &out[(bbase + s/30)*30 + s%30]);
}

// ---------------- fallback (ws too small): correct but slow fp32 ----------------
__global__ void __launch_bounds__(256)
vae_naive(const float* __restrict__ initial_c, const float* __restrict__ initial_s,
          const float* __restrict__ current_c, const float* __restrict__ eps,
          const float* eW0, const float* eb0, const float* eW1, const float* eb1,
          const float* Wm, const float* bm, const float* Wv, const float* bv,
          const float* dW0, const float* db0, const float* dW1, const float* db1,
          const float* dW2, const float* db2, float* out)
{
  __shared__ float xs[44], ds[41], h1[HID], h2[HID], rec[30];
  const int b = blockIdx.x, t = threadIdx.x;
  if (t < 30) rec[t] = 0.f;
  for (int o = 0; o < NOBJ; ++o) {
    __syncthreads();
    if (t < 44) {
      float v;
      if      (t < 5)  v = (t == o) ? 1.f : 0.f;
      else if (t < 20) v = initial_s[b*15 + (t-5)];
      else if (t < 32) v = initial_c[b*30 + d_OIDS[o][t-20]];
      else             v = current_c[b*30 + d_OIDS[o][t-32]];
      xs[t] = v;
    }
    __syncthreads();
    for (int h = t; h < HID; h += 256) {
      float a = eb0[h];
      for (int k = 0; k < 44; ++k) a = fmaf(xs[k], eW0[h*44+k], a);
      h1[h] = fmaxf(a, 0.f);
    }
    __syncthreads();
    for (int h = t; h < HID; h += 256) {
      float a = eb1[h];
      for (int k = 0; k < HID; ++k) a = fmaf(h1[k], eW1[h*512+k], a);
      h2[h] = fmaxf(a, 0.f);
    }
    __syncthreads();
    if (t < 9) {
      float am = bm[t], av = bv[t];
      for (int k = 0; k < HID; ++k) { am = fmaf(h2[k], Wm[t*512+k], am); av = fmaf(h2[k], Wv[t*512+k], av); }
      const int gid = (o*BATCH + b)*9 + t;
      out[OUT_MEANS + gid] = am;
      out[OUT_LV    + gid] = av;
      const float zz = fmaf(eps[gid], expf(0.5f*av), am);
      out[OUT_Z     + gid] = zz;
      ds[5+t] = zz;
    }
    if (t < 41 && (t < 5 || t >= 14)) {
      float v;
      if      (t < 5)  v = (t == o) ? 1.f : 0.f;
      else if (t < 29) v = initial_s[b*15 + (t-14)];
      else             v = initial_c[b*30 + d_OIDS[o][t-29]];
      ds[t] = v;
    }
    __syncthreads();
    for (int h = t; h < HID; h += 256) {
      float a = db0[h];
      for (int k = 0; k < 41; ++k) a = fmaf(ds[k], dW0[h*41+k], a);
      h1[h] = fmaxf(a, 0.f);
    }
    __syncthreads();
    for (int h = t; h < HID; h += 256) {
      float a = db1[h];
      for (int k = 0; k < HID; ++k) a = fmaf(h1[k], dW1[h*512+k], a);
      h2[h] = fmaxf(a, 0.f);
    }
    __syncthreads();
    if (t < 12) {
      float a = db2[t];
      for (int k = 0; k < HID; ++k) a = fmaf(h2[k], dW2[t*512+k], a);
      rec[d_OIDS[o][t]] += 1.f / (1.f + expf(-a));
    }
  }
  __syncthreads();
  if (t < 30) out[b*30+t] = rec[t];
}

extern "C" void kernel_launch(void* const* d_in, const int* in_sizes, int n_in,
                              void* d_out, int out_size, void* d_ws, size_t ws_size,
                              hipStream_t stream)
{
  const float* initial_c = (const float*)d_in[0];
  const float* initial_s = (const float*)d_in[1];
  const float* current_c = (const float*)d_in[2];
  const float* eps       = (const float*)d_in[3];
  const float* eW0 = (const float*)d_in[4];
  const float* eb0 = (const float*)d_in[5];
  const float* eW1 = (const float*)d_in[6];
  const float* eb1 = (const float*)d_in[7];
  const float* Wm  = (const float*)d_in[8];
  const float* bm  = (const float*)d_in[9];
  const float* Wv  = (const float*)d_in[10];
  const float* bv  = (const float*)d_in[11];
  const float* dW0 = (const float*)d_in[12];
  const float* db0 = (const float*)d_in[13];
  const float* dW1 = (const float*)d_in[14];
  const float* db1 = (const float*)d_in[15];
  const float* dW2 = (const float*)d_in[16];
  const float* db2 = (const float*)d_in[17];
  float* out = (float*)d_out;

  if (ws_size >= (size_t)UO_TOTAL * sizeof(unsigned short)) {
    unsigned short* ws = (unsigned short*)d_ws;
    prep_bf16<<<1024, 256, 0, stream>>>(eW0, eW1, Wm, Wv, dW0, dW1, dW2, ws);
    vae_mfma<<<BATCH/TM, 512, 0, stream>>>(initial_c, initial_s, current_c, eps,
                                           eb0, eb1, bm, bv, db0, db1, db2, ws, out);
  } else {
    vae_naive<<<BATCH, 256, 0, stream>>>(initial_c, initial_s, current_c, eps,
                                         eW0, eb0, eW1, eb1, Wm, bm, Wv, bv,
                                         dW0, db0, dW1, db1, dW2, db2, out);
  }
}

// Round 5
// 814.252 us; speedup vs baseline: 2.3431x; 1.0693x over previous
//
#include <hip/hip_runtime.h>
#include <math.h>

// ---------------- problem constants ----------------
#define BATCH 32768
#define HID   512
#define NOBJ  5
#define TM    64            // batch rows per block (MFMA path), 256 threads
#define NBT   (BATCH/TM)    // 512 batch tiles

typedef __attribute__((ext_vector_type(8))) short bf16x8;
typedef __attribute__((ext_vector_type(4))) float f32x4;

__device__ __constant__ int d_OIDS[5][12] = {
  {0,1,2,3, 10,11,12,13,14,18,22,26},
  {0,4,5,6, 10,14,15,16,17,19,23,27},
  {1,4,7,8, 11,15,18,19,20,21,24,28},
  {2,5,7,9, 12,16,20,22,23,24,25,29},
  {3,6,8,9, 13,17,21,25,26,27,28,29}
};

// ---------------- bf16 weight workspace (ushort offsets) ----------------
#define UO_EW0   0                       // [512][64]  (K padded 44->64)
#define UO_EW1   (UO_EW0 + 512*64)       // [512][512]
#define UO_HEADS (UO_EW1 + 512*512)      // [32][512]: rows 0-8 Wm, 16-24 Wv, rest 0
#define UO_DW0   (UO_HEADS + 32*512)     // [512][64]  (K padded 41->64)
#define UO_DW1   (UO_DW0 + 512*64)       // [512][512]
#define UO_DW2   (UO_DW1 + 512*512)      // [16][512]: rows 0-11 dec_W2, rest 0
#define UO_TOTAL (UO_DW2 + 16*512)       // 614400 ushorts = 1.23 MB

// ---------------- output layout (floats) ----------------
#define OUT_MEANS (BATCH*30)
#define OUT_LV    (OUT_MEANS + NOBJ*BATCH*9)
#define OUT_Z     (OUT_LV    + NOBJ*BATCH*9)

// round-to-nearest-even f32 -> bf16 bits
__device__ __forceinline__ unsigned short f2b(float x) {
  unsigned int u = __builtin_bit_cast(unsigned int, x);
  u += 0x7FFFu + ((u >> 16) & 1u);
  return (unsigned short)(u >> 16);
}

// ---------------- prep: convert/pad weights into ws (bf16) ----------------
__global__ void __launch_bounds__(256)
prep_bf16(const float* __restrict__ eW0, const float* __restrict__ eW1,
          const float* __restrict__ Wm,  const float* __restrict__ Wv,
          const float* __restrict__ dW0, const float* __restrict__ dW1,
          const float* __restrict__ dW2, unsigned short* __restrict__ ws)
{
  for (int i = blockIdx.x*blockDim.x + threadIdx.x; i < UO_TOTAL; i += gridDim.x*blockDim.x) {
    float v = 0.f; int j;
    if (i < UO_EW1) {                       // [512][64] <- eW0 [512][44]
      j = i - UO_EW0; int h = j >> 6, k = j & 63;
      if (k < 44) v = eW0[h*44 + k];
    } else if (i < UO_HEADS) {              // [512][512] <- eW1
      j = i - UO_EW1; v = eW1[j];
    } else if (i < UO_DW0) {                // [32][512] heads
      j = i - UO_HEADS; int r = j >> 9, k = j & 511;
      if (r < 9)                  v = Wm[r*512 + k];
      else if (r >= 16 && r < 25) v = Wv[(r-16)*512 + k];
    } else if (i < UO_DW1) {                // [512][64] <- dW0 [512][41]
      j = i - UO_DW0; int h = j >> 6, k = j & 63;
      if (k < 41) v = dW0[h*41 + k];
    } else if (i < UO_DW2) {                // [512][512] <- dW1
      j = i - UO_DW1; v = dW1[j];
    } else {                                // [16][512] <- dW2 [12][512]
      j = i - UO_DW2; int r = j >> 9, k = j & 511;
      if (r < 12) v = dW2[r*512 + k];
    }
    ws[i] = f2b(v);
  }
}

// One dense layer via MFMA: out[64][512] = relu(in[64][K] * W^T + bias)
// 4 waves, 1M x 4N: wave covers ALL 64 rows x cols [wave*128, +128).
// B (global) is ping-pong double-buffered in registers: global-load latency
// hides under the previous half-step's 32 MFMAs. #pragma unroll 1 bounds the
// live set (acc128 + b0/b1 64 + a 16 ~ 235 regs, no spills).
// In-place (sIn==sOut) safe: reads complete before mid-barrier.
template<int KT, int ROWW>   // K = KT*32, KT even
__device__ __forceinline__ void layer_mfma(const unsigned short* sIn,
                                           const unsigned short* __restrict__ Wb,
                                           const float* __restrict__ bias,
                                           unsigned short* sOut,
                                           int wave, int lane)
{
  const int lcol = lane & 15;
  const int lk   = (lane >> 4) * 8;
  const int colbase = wave * 128;

  f32x4 acc[4][8];
  #pragma unroll
  for (int n = 0; n < 8; ++n) {
    const float bv = bias[colbase + n*16 + lcol];
    #pragma unroll
    for (int m = 0; m < 4; ++m) acc[m][n] = (f32x4){bv, bv, bv, bv};
  }

  const unsigned short* wp = Wb + (colbase + lcol)*(KT*32) + lk;
  bf16x8 b0[8], b1[8], a[4];
  #pragma unroll
  for (int n = 0; n < 8; ++n)
    b0[n] = *(const bf16x8*)(wp + n*16*(KT*32));

  #pragma unroll 1
  for (int kt = 0; kt < KT; kt += 2) {
    // prefetch kt+1 (always exists: KT even)
    #pragma unroll
    for (int n = 0; n < 8; ++n)
      b1[n] = *(const bf16x8*)(wp + n*16*(KT*32) + (kt+1)*32);
    {
      const int k0 = kt*32 + lk;
      #pragma unroll
      for (int m = 0; m < 4; ++m) {
        const int row = m*16 + lcol;
        a[m] = *(const bf16x8*)&sIn[row*ROWW + (k0 ^ ((row & 7) << 3))];
      }
      #pragma unroll
      for (int n = 0; n < 8; ++n)
        #pragma unroll
        for (int m = 0; m < 4; ++m)
          acc[m][n] = __builtin_amdgcn_mfma_f32_16x16x32_bf16(a[m], b0[n], acc[m][n], 0, 0, 0);
    }
    if (kt + 2 < KT) {       // prefetch kt+2
      #pragma unroll
      for (int n = 0; n < 8; ++n)
        b0[n] = *(const bf16x8*)(wp + n*16*(KT*32) + (kt+2)*32);
    }
    {
      const int k1 = (kt+1)*32 + lk;
      #pragma unroll
      for (int m = 0; m < 4; ++m) {
        const int row = m*16 + lcol;
        a[m] = *(const bf16x8*)&sIn[row*ROWW + (k1 ^ ((row & 7) << 3))];
      }
      #pragma unroll
      for (int n = 0; n < 8; ++n)
        #pragma unroll
        for (int m = 0; m < 4; ++m)
          acc[m][n] = __builtin_amdgcn_mfma_f32_16x16x32_bf16(a[m], b1[n], acc[m][n], 0, 0, 0);
    }
  }

  __syncthreads();   // all reads of sIn done before (possibly aliased) writes
  const int rbase = (lane >> 4) * 4;
  #pragma unroll
  for (int m = 0; m < 4; ++m)
    #pragma unroll
    for (int n = 0; n < 8; ++n) {
      const int col = colbase + n*16 + lcol;
      #pragma unroll
      for (int r = 0; r < 4; ++r) {
        const int row = m*16 + rbase + r;
        sOut[row*512 + (col ^ ((row & 7) << 3))] = f2b(fmaxf(acc[m][n][r], 0.f));
      }
    }
  __syncthreads();
}

// grid = NOBJ * NBT blocks; block = one (object, 64-row batch tile).
__global__ void __launch_bounds__(256, 2)
vae_mfma(const float* __restrict__ initial_c, const float* __restrict__ initial_s,
         const float* __restrict__ current_c, const float* __restrict__ eps,
         const float* __restrict__ enc_b0, const float* __restrict__ enc_b1,
         const float* __restrict__ bm, const float* __restrict__ bv,
         const float* __restrict__ dec_b0, const float* __restrict__ dec_b1,
         const float* __restrict__ dec_b2, const unsigned short* __restrict__ ws,
         float* __restrict__ out)
{
  __shared__ __align__(16) unsigned short s_act[TM*512];  // 64 KB activations (in-place)
  __shared__ __align__(16) unsigned short s_in[TM*64];    // 8 KB enc/dec input (K pad 64)
  // total 72 KB -> 2 independent blocks/CU

  const int t = threadIdx.x;
  const int wave = t >> 6, lane = t & 63;
  const int lcol = lane & 15, lk = (lane >> 4) * 8, rbase = (lane >> 4) * 4;
  const int o     = blockIdx.x >> 9;          // NBT==512
  const int bbase = (blockIdx.x & 511) * TM;

  // ---- encoder input [64][64]: [oh 0-4 | s 5-19 | gi 20-31 | gc 32-43 | 0] ----
  for (int s = t; s < TM*64; s += 256) {
    const int row = s >> 6, col = s & 63;
    float v = 0.f;
    if (col < 5)       v = (col == o) ? 1.f : 0.f;
    else if (col < 20) v = initial_s[(bbase+row)*15 + col - 5];
    else if (col < 32) v = initial_c[(bbase+row)*30 + d_OIDS[o][col-20]];
    else if (col < 44) v = current_c[(bbase+row)*30 + d_OIDS[o][col-32]];
    s_in[row*64 + (col ^ ((row & 7) << 3))] = f2b(v);
  }
  __syncthreads();

  layer_mfma<2, 64>  (s_in,  ws + UO_EW0, enc_b0, s_act, wave, lane);  // h1
  layer_mfma<16, 512>(s_act, ws + UO_EW1, enc_b1, s_act, wave, lane);  // h2 in-place

  // ---- heads: means / log_var / z (wave owns rows wave*16..+15) ----
  {
    // decoder input (non-z cols): [oh 0-4 | z 5-13 | s 14-28 | gi 29-40 | 0]
    for (int s = t; s < TM*64; s += 256) {
      const int row = s >> 6, col = s & 63;
      if (col >= 5 && col < 14) continue;
      float v = 0.f;
      if (col < 5)       v = (col == o) ? 1.f : 0.f;
      else if (col < 29) v = initial_s[(bbase+row)*15 + col - 14];
      else if (col < 41) v = initial_c[(bbase+row)*30 + d_OIDS[o][col-29]];
      s_in[row*64 + (col ^ ((row & 7) << 3))] = f2b(v);
    }
    const float bmv = (lcol < 9) ? bm[lcol] : 0.f;
    const float bvv = (lcol < 9) ? bv[lcol] : 0.f;
    f32x4 am = (f32x4){bmv, bmv, bmv, bmv};
    f32x4 av = (f32x4){bvv, bvv, bvv, bvv};
    const unsigned short* hpM = ws + UO_HEADS + lcol*512 + lk;
    const unsigned short* hpV = hpM + 16*512;
    const int hrow = wave*16 + lcol;
    #pragma unroll 1
    for (int kt = 0; kt < 16; ++kt) {
      const int k0 = kt*32 + lk;
      bf16x8 a  = *(const bf16x8*)&s_act[hrow*512 + (k0 ^ ((hrow & 7) << 3))];
      bf16x8 bM = *(const bf16x8*)(hpM + kt*32);
      bf16x8 bV = *(const bf16x8*)(hpV + kt*32);
      am = __builtin_amdgcn_mfma_f32_16x16x32_bf16(a, bM, am, 0, 0, 0);
      av = __builtin_amdgcn_mfma_f32_16x16x32_bf16(a, bV, av, 0, 0, 0);
    }
    __syncthreads();   // all head reads of s_act done -> stage area free
    float* stage = (float*)s_act;        // [3][64][9] f32 = 6.9 KB
    if (lcol < 9) {
      #pragma unroll
      for (int r = 0; r < 4; ++r) {
        const int row = wave*16 + rbase + r;
        const int gid = (o*BATCH + bbase + row)*9 + lcol;
        const float m_ = am[r], v_ = av[r];
        const float zz = fmaf(eps[gid], expf(0.5f*v_), m_);
        stage[       row*9 + lcol] = m_;
        stage[576 +  row*9 + lcol] = v_;
        stage[1152 + row*9 + lcol] = zz;
        s_in[row*64 + ((5 + lcol) ^ ((row & 7) << 3))] = f2b(zz);
      }
    }
    __syncthreads();
    // coalesced nontemporal head-output writes (contiguous 2.3 KB each)
    const int ob_m = OUT_MEANS + (o*BATCH + bbase)*9;
    const int ob_v = OUT_LV    + (o*BATCH + bbase)*9;
    const int ob_z = OUT_Z     + (o*BATCH + bbase)*9;
    for (int i = t; i < TM*9; i += 256) {
      __builtin_nontemporal_store(stage[i],        &out[ob_m + i]);
      __builtin_nontemporal_store(stage[576 + i],  &out[ob_v + i]);
      __builtin_nontemporal_store(stage[1152 + i], &out[ob_z + i]);
    }
    // dec0's internal mid-barrier orders the s_act overwrite after these reads
  }

  layer_mfma<2, 64>  (s_in,  ws + UO_DW0, dec_b0, s_act, wave, lane);  // g1
  layer_mfma<16, 512>(s_act, ws + UO_DW1, dec_b1, s_act, wave, lane);  // g2 in-place

  // ---- dec head: sigmoid + atomic scatter (exactly 2 adds/element overall) ----
  {
    const float b2 = (lcol < 12) ? dec_b2[lcol] : 0.f;
    f32x4 acc = (f32x4){b2, b2, b2, b2};
    const unsigned short* wp = ws + UO_DW2 + lcol*512 + lk;
    const int hrow = wave*16 + lcol;
    #pragma unroll 1
    for (int kt = 0; kt < 16; ++kt) {
      const int k0 = kt*32 + lk;
      bf16x8 a = *(const bf16x8*)&s_act[hrow*512 + (k0 ^ ((hrow & 7) << 3))];
      bf16x8 b = *(const bf16x8*)(wp + kt*32);
      acc = __builtin_amdgcn_mfma_f32_16x16x32_bf16(a, b, acc, 0, 0, 0);
    }
    if (lcol < 12) {
      const int c30 = d_OIDS[o][lcol];
      #pragma unroll
      for (int r = 0; r < 4; ++r) {
        const int row = wave*16 + rbase + r;
        atomicAdd(&out[(bbase + row)*30 + c30], 1.f / (1.f + expf(-acc[r])));
      }
    }
  }
}

// ---------------- fallback (ws too small): correct but slow fp32 ----------------
__global__ void __launch_bounds__(256)
vae_naive(const float* __restrict__ initial_c, const float* __restrict__ initial_s,
          const float* __restrict__ current_c, const float* __restrict__ eps,
          const float* eW0, const float* eb0, const float* eW1, const float* eb1,
          const float* Wm, const float* bm, const float* Wv, const float* bv,
          const float* dW0, const float* db0, const float* dW1, const float* db1,
          const float* dW2, const float* db2, float* out)
{
  __shared__ float xs[44], ds[41], h1[HID], h2[HID], rec[30];
  const int b = blockIdx.x, t = threadIdx.x;
  if (t < 30) rec[t] = 0.f;
  for (int o = 0; o < NOBJ; ++o) {
    __syncthreads();
    if (t < 44) {
      float v;
      if      (t < 5)  v = (t == o) ? 1.f : 0.f;
      else if (t < 20) v = initial_s[b*15 + (t-5)];
      else if (t < 32) v = initial_c[b*30 + d_OIDS[o][t-20]];
      else             v = current_c[b*30 + d_OIDS[o][t-32]];
      xs[t] = v;
    }
    __syncthreads();
    for (int h = t; h < HID; h += 256) {
      float a = eb0[h];
      for (int k = 0; k < 44; ++k) a = fmaf(xs[k], eW0[h*44+k], a);
      h1[h] = fmaxf(a, 0.f);
    }
    __syncthreads();
    for (int h = t; h < HID; h += 256) {
      float a = eb1[h];
      for (int k = 0; k < HID; ++k) a = fmaf(h1[k], eW1[h*512+k], a);
      h2[h] = fmaxf(a, 0.f);
    }
    __syncthreads();
    if (t < 9) {
      float am = bm[t], av = bv[t];
      for (int k = 0; k < HID; ++k) { am = fmaf(h2[k], Wm[t*512+k], am); av = fmaf(h2[k], Wv[t*512+k], av); }
      const int gid = (o*BATCH + b)*9 + t;
      out[OUT_MEANS + gid] = am;
      out[OUT_LV    + gid] = av;
      const float zz = fmaf(eps[gid], expf(0.5f*av), am);
      out[OUT_Z     + gid] = zz;
      ds[5+t] = zz;
    }
    if (t < 41 && (t < 5 || t >= 14)) {
      float v;
      if      (t < 5)  v = (t == o) ? 1.f : 0.f;
      else if (t < 29) v = initial_s[b*15 + (t-14)];
      else             v = initial_c[b*30 + d_OIDS[o][t-29]];
      ds[t] = v;
    }
    __syncthreads();
    for (int h = t; h < HID; h += 256) {
      float a = db0[h];
      for (int k = 0; k < 41; ++k) a = fmaf(ds[k], dW0[h*41+k], a);
      h1[h] = fmaxf(a, 0.f);
    }
    __syncthreads();
    for (int h = t; h < HID; h += 256) {
      float a = db1[h];
      for (int k = 0; k < HID; ++k) a = fmaf(h1[k], dW1[h*512+k], a);
      h2[h] = fmaxf(a, 0.f);
    }
    __syncthreads();
    if (t < 12) {
      float a = db2[t];
      for (int k = 0; k < HID; ++k) a = fmaf(h2[k], dW2[t*512+k], a);
      rec[d_OIDS[o][t]] += 1.f / (1.f + expf(-a));
    }
  }
  __syncthreads();
  if (t < 30) out[b*30+t] = rec[t];
}

extern "C" void kernel_launch(void* const* d_in, const int* in_sizes, int n_in,
                              void* d_out, int out_size, void* d_ws, size_t ws_size,
                              hipStream_t stream)
{
  const float* initial_c = (const float*)d_in[0];
  const float* initial_s = (const float*)d_in[1];
  const float* current_c = (const float*)d_in[2];
  const float* eps       = (const float*)d_in[3];
  const float* eW0 = (const float*)d_in[4];
  const float* eb0 = (const float*)d_in[5];
  const float* eW1 = (const float*)d_in[6];
  const float* eb1 = (const float*)d_in[7];
  const float* Wm  = (const float*)d_in[8];
  const float* bm  = (const float*)d_in[9];
  const float* Wv  = (const float*)d_in[10];
  const float* bv  = (const float*)d_in[11];
  const float* dW0 = (const float*)d_in[12];
  const float* db0 = (const float*)d_in[13];
  const float* dW1 = (const float*)d_in[14];
  const float* db1 = (const float*)d_in[15];
  const float* dW2 = (const float*)d_in[16];
  const float* db2 = (const float*)d_in[17];
  float* out = (float*)d_out;

  if (ws_size >= (size_t)UO_TOTAL * sizeof(unsigned short)) {
    unsigned short* ws = (unsigned short*)d_ws;
    prep_bf16<<<1024, 256, 0, stream>>>(eW0, eW1, Wm, Wv, dW0, dW1, dW2, ws);
    // zero the reconstructed region (atomics accumulate into it)
    hipMemsetAsync(out, 0, (size_t)BATCH * 30 * sizeof(float), stream);
    vae_mfma<<<NOBJ*NBT, 256, 0, stream>>>(initial_c, initial_s, current_c, eps,
                                           eb0, eb1, bm, bv, db0, db1, db2, ws, out);
  } else {
    vae_naive<<<BATCH, 256, 0, stream>>>(initial_c, initial_s, current_c, eps,
                                         eW0, eb0, eW1, eb1, Wm, bm, Wv, bv,
                                         dW0, db0, dW1, db1, dW2, db2, out);
  }
}

// Round 6
// 755.450 us; speedup vs baseline: 2.5255x; 1.0778x over previous
//
#include <hip/hip_runtime.h>
#include <math.h>

// ---------------- problem constants ----------------
#define BATCH 32768
#define HID   512
#define NOBJ  5
#define TM    32            // batch rows per block (MFMA path), 512 threads
#define NBT   (BATCH/TM)    // 1024 batch tiles

typedef __attribute__((ext_vector_type(8))) short bf16x8;
typedef __attribute__((ext_vector_type(4))) float f32x4;

__device__ __constant__ int d_OIDS[5][12] = {
  {0,1,2,3, 10,11,12,13,14,18,22,26},
  {0,4,5,6, 10,14,15,16,17,19,23,27},
  {1,4,7,8, 11,15,18,19,20,21,24,28},
  {2,5,7,9, 12,16,20,22,23,24,25,29},
  {3,6,8,9, 13,17,21,25,26,27,28,29}
};

// ---------------- bf16 weight workspace (ushort offsets) ----------------
#define UO_EW0   0                       // [512][64]  (K padded 44->64)
#define UO_EW1   (UO_EW0 + 512*64)       // [512][512]
#define UO_HEADS (UO_EW1 + 512*512)      // [32][512]: rows 0-8 Wm, 16-24 Wv, rest 0
#define UO_DW0   (UO_HEADS + 32*512)     // [512][64]  (K padded 41->64)
#define UO_DW1   (UO_DW0 + 512*64)       // [512][512]
#define UO_DW2   (UO_DW1 + 512*512)      // [16][512]: rows 0-11 dec_W2, rest 0
#define UO_TOTAL (UO_DW2 + 16*512)       // 614400 ushorts = 1.23 MB

// ---------------- output layout (floats) ----------------
#define OUT_MEANS (BATCH*30)
#define OUT_LV    (OUT_MEANS + NOBJ*BATCH*9)
#define OUT_Z     (OUT_LV    + NOBJ*BATCH*9)

// round-to-nearest-even f32 -> bf16 bits
__device__ __forceinline__ unsigned short f2b(float x) {
  unsigned int u = __builtin_bit_cast(unsigned int, x);
  u += 0x7FFFu + ((u >> 16) & 1u);
  return (unsigned short)(u >> 16);
}

// ---------------- prep: convert/pad weights into ws (bf16) ----------------
__global__ void __launch_bounds__(256)
prep_bf16(const float* __restrict__ eW0, const float* __restrict__ eW1,
          const float* __restrict__ Wm,  const float* __restrict__ Wv,
          const float* __restrict__ dW0, const float* __restrict__ dW1,
          const float* __restrict__ dW2, unsigned short* __restrict__ ws)
{
  for (int i = blockIdx.x*blockDim.x + threadIdx.x; i < UO_TOTAL; i += gridDim.x*blockDim.x) {
    float v = 0.f; int j;
    if (i < UO_EW1) {                       // [512][64] <- eW0 [512][44]
      j = i - UO_EW0; int h = j >> 6, k = j & 63;
      if (k < 44) v = eW0[h*44 + k];
    } else if (i < UO_HEADS) {              // [512][512] <- eW1
      j = i - UO_EW1; v = eW1[j];
    } else if (i < UO_DW0) {                // [32][512] heads
      j = i - UO_HEADS; int r = j >> 9, k = j & 511;
      if (r < 9)                  v = Wm[r*512 + k];
      else if (r >= 16 && r < 25) v = Wv[(r-16)*512 + k];
    } else if (i < UO_DW1) {                // [512][64] <- dW0 [512][41]
      j = i - UO_DW0; int h = j >> 6, k = j & 63;
      if (k < 41) v = dW0[h*41 + k];
    } else if (i < UO_DW2) {                // [512][512] <- dW1
      j = i - UO_DW1; v = dW1[j];
    } else {                                // [16][512] <- dW2 [12][512]
      j = i - UO_DW2; int r = j >> 9, k = j & 511;
      if (r < 12) v = dW2[r*512 + k];
    }
    ws[i] = f2b(v);
  }
}

// One dense layer via MFMA: out[32][512] = relu(in[32][K] * W^T + bias)
// 8 waves, 1M x 8N: wave covers ALL 32 rows x cols [wave*64, +64).
// acc[2][4] = 32 AGPRs; arch live set (b0/b1[4]=32, a[2]=8, addr) ~90
// -> fits the 128-reg cap of __launch_bounds__(512,4) with margin: NO SPILLS.
// B ping-pong double-buffer hides L2 latency under the previous 16 MFMAs.
// In-place (sIn==sOut) safe: reads complete before mid-barrier.
template<int KT, int ROWW>   // K = KT*32, KT even
__device__ __forceinline__ void layer_mfma(const unsigned short* sIn,
                                           const unsigned short* __restrict__ Wb,
                                           const float* __restrict__ bias,
                                           unsigned short* sOut,
                                           int wave, int lane)
{
  const int lcol = lane & 15;
  const int lk   = (lane >> 4) * 8;
  const int colbase = wave * 64;

  f32x4 acc[2][4];
  #pragma unroll
  for (int n = 0; n < 4; ++n) {
    const float bv = bias[colbase + n*16 + lcol];
    #pragma unroll
    for (int m = 0; m < 2; ++m) acc[m][n] = (f32x4){bv, bv, bv, bv};
  }

  const unsigned short* wp = Wb + (colbase + lcol)*(KT*32) + lk;
  const int swz = (lcol & 7) << 3;    // row&7 == lcol&7 for rows m*16+lcol
  bf16x8 b0[4], b1[4], a[2];
  #pragma unroll
  for (int n = 0; n < 4; ++n)
    b0[n] = *(const bf16x8*)(wp + n*16*(KT*32));

  #pragma unroll 1
  for (int kt = 0; kt < KT; kt += 2) {
    #pragma unroll
    for (int n = 0; n < 4; ++n)          // prefetch kt+1 (KT even: exists)
      b1[n] = *(const bf16x8*)(wp + n*16*(KT*32) + (kt+1)*32);
    {
      const int k0 = kt*32 + lk;
      #pragma unroll
      for (int m = 0; m < 2; ++m)
        a[m] = *(const bf16x8*)&sIn[(m*16 + lcol)*ROWW + (k0 ^ swz)];
      #pragma unroll
      for (int n = 0; n < 4; ++n)
        #pragma unroll
        for (int m = 0; m < 2; ++m)
          acc[m][n] = __builtin_amdgcn_mfma_f32_16x16x32_bf16(a[m], b0[n], acc[m][n], 0, 0, 0);
    }
    if (kt + 2 < KT) {                   // prefetch kt+2
      #pragma unroll
      for (int n = 0; n < 4; ++n)
        b0[n] = *(const bf16x8*)(wp + n*16*(KT*32) + (kt+2)*32);
    }
    {
      const int k1 = (kt+1)*32 + lk;
      #pragma unroll
      for (int m = 0; m < 2; ++m)
        a[m] = *(const bf16x8*)&sIn[(m*16 + lcol)*ROWW + (k1 ^ swz)];
      #pragma unroll
      for (int n = 0; n < 4; ++n)
        #pragma unroll
        for (int m = 0; m < 2; ++m)
          acc[m][n] = __builtin_amdgcn_mfma_f32_16x16x32_bf16(a[m], b1[n], acc[m][n], 0, 0, 0);
    }
  }

  __syncthreads();   // all reads of sIn done before (possibly aliased) writes
  const int rbase = (lane >> 4) * 4;
  #pragma unroll
  for (int m = 0; m < 2; ++m)
    #pragma unroll
    for (int n = 0; n < 4; ++n) {
      const int col = colbase + n*16 + lcol;
      #pragma unroll
      for (int r = 0; r < 4; ++r) {
        const int row = m*16 + rbase + r;
        sOut[row*512 + (col ^ ((row & 7) << 3))] = f2b(fmaxf(acc[m][n][r], 0.f));
      }
    }
  __syncthreads();
}

// grid = NOBJ * NBT blocks; block = one (object, 32-row batch tile).
__global__ void __launch_bounds__(512, 4)
vae_mfma(const float* __restrict__ initial_c, const float* __restrict__ initial_s,
         const float* __restrict__ current_c, const float* __restrict__ eps,
         const float* __restrict__ enc_b0, const float* __restrict__ enc_b1,
         const float* __restrict__ bm, const float* __restrict__ bv,
         const float* __restrict__ dec_b0, const float* __restrict__ dec_b1,
         const float* __restrict__ dec_b2, const unsigned short* __restrict__ ws,
         float* __restrict__ out)
{
  __shared__ __align__(16) unsigned short s_act[TM*512];  // 32 KB activations (in-place)
  __shared__ __align__(16) unsigned short s_in[TM*64];    // 4 KB enc/dec input (K pad 64)
  // total 36 KB; regs cap 128 -> 2 blocks/CU = 16 waves/CU (4/SIMD)

  const int t = threadIdx.x;
  const int wave = t >> 6, lane = t & 63;
  const int lcol = lane & 15, lk = (lane >> 4) * 8, rbase = (lane >> 4) * 4;
  const int o     = blockIdx.x >> 10;          // NBT==1024
  const int bbase = (blockIdx.x & 1023) * TM;

  // ---- encoder input [32][64]: [oh 0-4 | s 5-19 | gi 20-31 | gc 32-43 | 0] ----
  for (int s = t; s < TM*64; s += 512) {
    const int row = s >> 6, col = s & 63;
    float v = 0.f;
    if (col < 5)       v = (col == o) ? 1.f : 0.f;
    else if (col < 20) v = initial_s[(bbase+row)*15 + col - 5];
    else if (col < 32) v = initial_c[(bbase+row)*30 + d_OIDS[o][col-20]];
    else if (col < 44) v = current_c[(bbase+row)*30 + d_OIDS[o][col-32]];
    s_in[row*64 + (col ^ ((row & 7) << 3))] = f2b(v);
  }
  __syncthreads();

  layer_mfma<2, 64>  (s_in,  ws + UO_EW0, enc_b0, s_act, wave, lane);  // h1
  layer_mfma<16, 512>(s_act, ws + UO_EW1, enc_b1, s_act, wave, lane);  // h2 in-place

  // ---- heads: means / log_var / z (waves 0-1 own M-tiles; others idle-short) ----
  {
    // decoder input (non-z cols): [oh 0-4 | z 5-13 | s 14-28 | gi 29-40 | 0]
    for (int s = t; s < TM*64; s += 512) {
      const int row = s >> 6, col = s & 63;
      if (col >= 5 && col < 14) continue;
      float v = 0.f;
      if (col < 5)       v = (col == o) ? 1.f : 0.f;
      else if (col < 29) v = initial_s[(bbase+row)*15 + col - 14];
      else if (col < 41) v = initial_c[(bbase+row)*30 + d_OIDS[o][col-29]];
      s_in[row*64 + (col ^ ((row & 7) << 3))] = f2b(v);
    }
    f32x4 am, av;
    if (wave < 2) {
      const float bmv = (lcol < 9) ? bm[lcol] : 0.f;
      const float bvv = (lcol < 9) ? bv[lcol] : 0.f;
      am = (f32x4){bmv, bmv, bmv, bmv};
      av = (f32x4){bvv, bvv, bvv, bvv};
      const unsigned short* hpM = ws + UO_HEADS + lcol*512 + lk;
      const unsigned short* hpV = hpM + 16*512;
      const int hrow = wave*16 + lcol;
      #pragma unroll 1
      for (int kt = 0; kt < 16; ++kt) {
        const int k0 = kt*32 + lk;
        bf16x8 a  = *(const bf16x8*)&s_act[hrow*512 + (k0 ^ ((lcol & 7) << 3))];
        bf16x8 bM = *(const bf16x8*)(hpM + kt*32);
        bf16x8 bV = *(const bf16x8*)(hpV + kt*32);
        am = __builtin_amdgcn_mfma_f32_16x16x32_bf16(a, bM, am, 0, 0, 0);
        av = __builtin_amdgcn_mfma_f32_16x16x32_bf16(a, bV, av, 0, 0, 0);
      }
    }
    __syncthreads();   // all head reads of s_act done -> stage area free
    float* stage = (float*)s_act;        // [3][32][9] f32 = 3.4 KB
    if (wave < 2 && lcol < 9) {
      #pragma unroll
      for (int r = 0; r < 4; ++r) {
        const int row = wave*16 + rbase + r;
        const int gid = (o*BATCH + bbase + row)*9 + lcol;
        const float m_ = am[r], v_ = av[r];
        const float zz = fmaf(eps[gid], expf(0.5f*v_), m_);
        stage[      row*9 + lcol] = m_;
        stage[288 + row*9 + lcol] = v_;
        stage[576 + row*9 + lcol] = zz;
        s_in[row*64 + ((5 + lcol) ^ ((row & 7) << 3))] = f2b(zz);
      }
    }
    __syncthreads();
    // coalesced nontemporal head-output writes (contiguous 1.2 KB each)
    const int ob_m = OUT_MEANS + (o*BATCH + bbase)*9;
    const int ob_v = OUT_LV    + (o*BATCH + bbase)*9;
    const int ob_z = OUT_Z     + (o*BATCH + bbase)*9;
    if (t < TM*9) {
      __builtin_nontemporal_store(stage[t],       &out[ob_m + t]);
      __builtin_nontemporal_store(stage[288 + t], &out[ob_v + t]);
      __builtin_nontemporal_store(stage[576 + t], &out[ob_z + t]);
    }
    // dec0's internal mid-barrier orders the s_act overwrite after these reads
  }

  layer_mfma<2, 64>  (s_in,  ws + UO_DW0, dec_b0, s_act, wave, lane);  // g1
  layer_mfma<16, 512>(s_act, ws + UO_DW1, dec_b1, s_act, wave, lane);  // g2 in-place

  // ---- dec head: sigmoid + atomic scatter (exactly 2 adds/element overall) ----
  if (wave < 2) {
    const float b2 = (lcol < 12) ? dec_b2[lcol] : 0.f;
    f32x4 acc = (f32x4){b2, b2, b2, b2};
    const unsigned short* wp = ws + UO_DW2 + lcol*512 + lk;
    const int hrow = wave*16 + lcol;
    #pragma unroll 1
    for (int kt = 0; kt < 16; ++kt) {
      const int k0 = kt*32 + lk;
      bf16x8 a = *(const bf16x8*)&s_act[hrow*512 + (k0 ^ ((lcol & 7) << 3))];
      bf16x8 b = *(const bf16x8*)(wp + kt*32);
      acc = __builtin_amdgcn_mfma_f32_16x16x32_bf16(a, b, acc, 0, 0, 0);
    }
    if (lcol < 12) {
      const int c30 = d_OIDS[o][lcol];
      #pragma unroll
      for (int r = 0; r < 4; ++r) {
        const int row = wave*16 + rbase + r;
        atomicAdd(&out[(bbase + row)*30 + c30], 1.f / (1.f + expf(-acc[r])));
      }
    }
  }
}

// ---------------- fallback (ws too small): correct but slow fp32 ----------------
__global__ void __launch_bounds__(256)
vae_naive(const float* __restrict__ initial_c, const float* __restrict__ initial_s,
          const float* __restrict__ current_c, const float* __restrict__ eps,
          const float* eW0, const float* eb0, const float* eW1, const float* eb1,
          const float* Wm, const float* bm, const float* Wv, const float* bv,
          const float* dW0, const float* db0, const float* dW1, const float* db1,
          const float* dW2, const float* db2, float* out)
{
  __shared__ float xs[44], ds[41], h1[HID], h2[HID], rec[30];
  const int b = blockIdx.x, t = threadIdx.x;
  if (t < 30) rec[t] = 0.f;
  for (int o = 0; o < NOBJ; ++o) {
    __syncthreads();
    if (t < 44) {
      float v;
      if      (t < 5)  v = (t == o) ? 1.f : 0.f;
      else if (t < 20) v = initial_s[b*15 + (t-5)];
      else if (t < 32) v = initial_c[b*30 + d_OIDS[o][t-20]];
      else             v = current_c[b*30 + d_OIDS[o][t-32]];
      xs[t] = v;
    }
    __syncthreads();
    for (int h = t; h < HID; h += 256) {
      float a = eb0[h];
      for (int k = 0; k < 44; ++k) a = fmaf(xs[k], eW0[h*44+k], a);
      h1[h] = fmaxf(a, 0.f);
    }
    __syncthreads();
    for (int h = t; h < HID; h += 256) {
      float a = eb1[h];
      for (int k = 0; k < HID; ++k) a = fmaf(h1[k], eW1[h*512+k], a);
      h2[h] = fmaxf(a, 0.f);
    }
    __syncthreads();
    if (t < 9) {
      float am = bm[t], av = bv[t];
      for (int k = 0; k < HID; ++k) { am = fmaf(h2[k], Wm[t*512+k], am); av = fmaf(h2[k], Wv[t*512+k], av); }
      const int gid = (o*BATCH + b)*9 + t;
      out[OUT_MEANS + gid] = am;
      out[OUT_LV    + gid] = av;
      const float zz = fmaf(eps[gid], expf(0.5f*av), am);
      out[OUT_Z     + gid] = zz;
      ds[5+t] = zz;
    }
    if (t < 41 && (t < 5 || t >= 14)) {
      float v;
      if      (t < 5)  v = (t == o) ? 1.f : 0.f;
      else if (t < 29) v = initial_s[b*15 + (t-14)];
      else             v = initial_c[b*30 + d_OIDS[o][t-29]];
      ds[t] = v;
    }
    __syncthreads();
    for (int h = t; h < HID; h += 256) {
      float a = db0[h];
      for (int k = 0; k < 41; ++k) a = fmaf(ds[k], dW0[h*41+k], a);
      h1[h] = fmaxf(a, 0.f);
    }
    __syncthreads();
    for (int h = t; h < HID; h += 256) {
      float a = db1[h];
      for (int k = 0; k < HID; ++k) a = fmaf(h1[k], dW1[h*512+k], a);
      h2[h] = fmaxf(a, 0.f);
    }
    __syncthreads();
    if (t < 12) {
      float a = db2[t];
      for (int k = 0; k < HID; ++k) a = fmaf(h2[k], dW2[t*512+k], a);
      rec[d_OIDS[o][t]] += 1.f / (1.f + expf(-a));
    }
  }
  __syncthreads();
  if (t < 30) out[b*30+t] = rec[t];
}

extern "C" void kernel_launch(void* const* d_in, const int* in_sizes, int n_in,
                              void* d_out, int out_size, void* d_ws, size_t ws_size,
                              hipStream_t stream)
{
  const float* initial_c = (const float*)d_in[0];
  const float* initial_s = (const float*)d_in[1];
  const float* current_c = (const float*)d_in[2];
  const float* eps       = (const float*)d_in[3];
  const float* eW0 = (const float*)d_in[4];
  const float* eb0 = (const float*)d_in[5];
  const float* eW1 = (const float*)d_in[6];
  const float* eb1 = (const float*)d_in[7];
  const float* Wm  = (const float*)d_in[8];
  const float* bm  = (const float*)d_in[9];
  const float* Wv  = (const float*)d_in[10];
  const float* bv  = (const float*)d_in[11];
  const float* dW0 = (const float*)d_in[12];
  const float* db0 = (const float*)d_in[13];
  const float* dW1 = (const float*)d_in[14];
  const float* db1 = (const float*)d_in[15];
  const float* dW2 = (const float*)d_in[16];
  const float* db2 = (const float*)d_in[17];
  float* out = (float*)d_out;

  if (ws_size >= (size_t)UO_TOTAL * sizeof(unsigned short)) {
    unsigned short* ws = (unsigned short*)d_ws;
    prep_bf16<<<1024, 256, 0, stream>>>(eW0, eW1, Wm, Wv, dW0, dW1, dW2, ws);
    // zero the reconstructed region (atomics accumulate into it)
    hipMemsetAsync(out, 0, (size_t)BATCH * 30 * sizeof(float), stream);
    vae_mfma<<<NOBJ*NBT, 512, 0, stream>>>(initial_c, initial_s, current_c, eps,
                                           eb0, eb1, bm, bv, db0, db1, db2, ws, out);
  } else {
    vae_naive<<<BATCH, 256, 0, stream>>>(initial_c, initial_s, current_c, eps,
                                         eW0, eb0, eW1, eb1, Wm, bm, Wv, bv,
                                         dW0, db0, dW1, db1, dW2, db2, out);
  }
}

// Round 7
// 447.296 us; speedup vs baseline: 4.2654x; 1.6889x over previous
//
#include <hip/hip_runtime.h>
#include <math.h>

// ---------------- problem constants ----------------
#define BATCH 32768
#define HID   512
#define NOBJ  5
#define TM    64            // batch rows per block (MFMA path), 512 threads
#define NBT   (BATCH/TM)    // 512 batch tiles

typedef __attribute__((ext_vector_type(8))) short bf16x8;
typedef __attribute__((ext_vector_type(4))) float f32x4;

typedef const __attribute__((address_space(1))) void* gas1_t;
typedef __attribute__((address_space(3))) void* las3_t;

__device__ __constant__ int d_OIDS[5][12] = {
  {0,1,2,3, 10,11,12,13,14,18,22,26},
  {0,4,5,6, 10,14,15,16,17,19,23,27},
  {1,4,7,8, 11,15,18,19,20,21,24,28},
  {2,5,7,9, 12,16,20,22,23,24,25,29},
  {3,6,8,9, 13,17,21,25,26,27,28,29}
};

// ---------------- bf16 weight workspace (ushort offsets) ----------------
#define UO_EW0   0                       // [512][64]  (K padded 44->64)
#define UO_EW1   (UO_EW0 + 512*64)       // [512][512]
#define UO_HEADS (UO_EW1 + 512*512)      // [32][512]: rows 0-8 Wm, 16-24 Wv, rest 0
#define UO_DW0   (UO_HEADS + 32*512)     // [512][64]  (K padded 41->64)
#define UO_DW1   (UO_DW0 + 512*64)       // [512][512]
#define UO_DW2   (UO_DW1 + 512*512)      // [16][512]: rows 0-11 dec_W2, rest 0
#define UO_TOTAL (UO_DW2 + 16*512)       // 614400 ushorts = 1.23 MB

// ---------------- output layout (floats) ----------------
#define OUT_MEANS (BATCH*30)
#define OUT_LV    (OUT_MEANS + NOBJ*BATCH*9)
#define OUT_Z     (OUT_LV    + NOBJ*BATCH*9)

// round-to-nearest-even f32 -> bf16 bits
__device__ __forceinline__ unsigned short f2b(float x) {
  unsigned int u = __builtin_bit_cast(unsigned int, x);
  u += 0x7FFFu + ((u >> 16) & 1u);
  return (unsigned short)(u >> 16);
}

// ---------------- prep: convert/pad weights into ws (bf16) ----------------
__global__ void __launch_bounds__(256)
prep_bf16(const float* __restrict__ eW0, const float* __restrict__ eW1,
          const float* __restrict__ Wm,  const float* __restrict__ Wv,
          const float* __restrict__ dW0, const float* __restrict__ dW1,
          const float* __restrict__ dW2, unsigned short* __restrict__ ws)
{
  for (int i = blockIdx.x*blockDim.x + threadIdx.x; i < UO_TOTAL; i += gridDim.x*blockDim.x) {
    float v = 0.f; int j;
    if (i < UO_EW1) {                       // [512][64] <- eW0 [512][44]
      j = i - UO_EW0; int h = j >> 6, k = j & 63;
      if (k < 44) v = eW0[h*44 + k];
    } else if (i < UO_HEADS) {              // [512][512] <- eW1
      j = i - UO_EW1; v = eW1[j];
    } else if (i < UO_DW0) {                // [32][512] heads
      j = i - UO_HEADS; int r = j >> 9, k = j & 511;
      if (r < 9)                  v = Wm[r*512 + k];
      else if (r >= 16 && r < 25) v = Wv[(r-16)*512 + k];
    } else if (i < UO_DW1) {                // [512][64] <- dW0 [512][41]
      j = i - UO_DW0; int h = j >> 6, k = j & 63;
      if (k < 41) v = dW0[h*41 + k];
    } else if (i < UO_DW2) {                // [512][512] <- dW1
      j = i - UO_DW1; v = dW1[j];
    } else {                                // [16][512] <- dW2 [12][512]
      j = i - UO_DW2; int r = j >> 9, k = j & 511;
      if (r < 12) v = dW2[r*512 + k];
    }
    ws[i] = f2b(v);
  }
}

// ---- stage one 32-K B-tile [512 cols][32 k] into LDS via global_load_lds ----
// LDS dest is LINEAR (chunk c at byte c*16); global source chunk is fetched
// pre-swizzled (j' = j ^ (col&3)) so reads can apply the same XOR (rule 21).
// Wb is [col][KDIM] ushort; 2048 chunks of 16B; 512 threads -> 4 instrs each.
template<int KDIM>
__device__ __forceinline__ void stage_B(const unsigned short* __restrict__ Wb, int kt,
                                        unsigned short* buf, int t)
{
  #pragma unroll
  for (int i = 0; i < 4; ++i) {
    const int c   = i*512 + t;
    const int col = c >> 2, j = c & 3;
    const int jp  = j ^ (col & 3);
    const unsigned short* g = Wb + col*KDIM + kt*32 + jp*8;
    unsigned short* l = buf + (i*512 + (t & ~63)) * 8;   // wave-uniform base
    __builtin_amdgcn_global_load_lds((gas1_t)g, (las3_t)l, 16, 0, 0);
  }
}

// One dense layer: out[64][512] = relu(in[64][KT*32] * W^T + bias).
// 8 waves: wave covers rows 0..63 (4 M-tiles) x cols [wave*64,+64) (4 N-tiles).
// B double-buffered in LDS via global_load_lds (no VGPR round-trip); 2-phase
// loop: stage(next) -> ds_read+MFMA(cur) -> barrier (drains the async stage).
// In-place (sIn==sOut) safe: last K-step's barrier precedes epilogue writes.
template<int KT, int ROWW>
__device__ __forceinline__ void layer_mfma(const unsigned short* sIn,
                                           const unsigned short* __restrict__ Wb,
                                           const float* __restrict__ bias,
                                           unsigned short* sOut,
                                           unsigned short* sB,   // [2][512*32]
                                           int wave, int lane, int t)
{
  const int lcol = lane & 15;
  const int kg   = lane >> 4;
  const int lk   = kg * 8;
  const int colbase = wave * 64;

  f32x4 acc[4][4];
  #pragma unroll
  for (int n = 0; n < 4; ++n) {
    const float bv = bias[colbase + n*16 + lcol];
    #pragma unroll
    for (int m = 0; m < 4; ++m) acc[m][n] = (f32x4){bv, bv, bv, bv};
  }

  stage_B<KT*32>(Wb, 0, sB, t);
  __syncthreads();                       // drain prologue stage

  int cur = 0;
  #pragma unroll 1
  for (int kt = 0; kt < KT; ++kt) {
    if (kt + 1 < KT) stage_B<KT*32>(Wb, kt + 1, sB + (cur ^ 1)*512*32, t);
    const unsigned short* bb = sB + cur*512*32;
    const int k0 = kt*32 + lk;
    bf16x8 a[4];
    #pragma unroll
    for (int m = 0; m < 4; ++m) {
      const int row = m*16 + lcol;
      a[m] = *(const bf16x8*)&sIn[row*ROWW + (k0 ^ ((row & 7) << 3))];
    }
    #pragma unroll
    for (int n = 0; n < 4; ++n) {
      const int col = colbase + n*16 + lcol;
      const bf16x8 b = *(const bf16x8*)&bb[col*32 + ((kg ^ (col & 3)) * 8)];
      #pragma unroll
      for (int m = 0; m < 4; ++m)
        acc[m][n] = __builtin_amdgcn_mfma_f32_16x16x32_bf16(a[m], b, acc[m][n], 0, 0, 0);
    }
    __syncthreads();                     // next buffer staged + cur reads done
    cur ^= 1;
  }

  const int rbase = kg * 4;
  #pragma unroll
  for (int m = 0; m < 4; ++m)
    #pragma unroll
    for (int n = 0; n < 4; ++n) {
      const int col = colbase + n*16 + lcol;
      #pragma unroll
      for (int r = 0; r < 4; ++r) {
        const int row = m*16 + rbase + r;
        sOut[row*512 + (col ^ ((row & 7) << 3))] = f2b(fmaxf(acc[m][n][r], 0.f));
      }
    }
  __syncthreads();
}

// grid = NOBJ * NBT blocks; block = one (object, 64-row batch tile).
__global__ void __launch_bounds__(512, 2)
vae_mfma(const float* __restrict__ initial_c, const float* __restrict__ initial_s,
         const float* __restrict__ current_c, const float* __restrict__ eps,
         const float* __restrict__ enc_b0, const float* __restrict__ enc_b1,
         const float* __restrict__ bm, const float* __restrict__ bv,
         const float* __restrict__ dec_b0, const float* __restrict__ dec_b1,
         const float* __restrict__ dec_b2, const unsigned short* __restrict__ ws,
         float* __restrict__ out)
{
  __shared__ __align__(16) unsigned short s_act[TM*512];    // 64 KB activations
  __shared__ __align__(16) unsigned short s_bs[2*512*32];   // 64 KB B double-buffer
  __shared__ __align__(16) unsigned short s_in[TM*64];      // 8 KB enc/dec input
  // 136 KB -> 1 block/CU, 8 waves (2/SIMD)

  const int t = threadIdx.x;
  const int wave = t >> 6, lane = t & 63;
  const int lcol = lane & 15, kg = lane >> 4;
  const int lk = kg * 8, rbase = kg * 4;
  const int o     = blockIdx.x / NBT;
  const int bbase = (blockIdx.x % NBT) * TM;

  // ---- encoder input [64][64]: [oh 0-4 | s 5-19 | gi 20-31 | gc 32-43 | 0] ----
  for (int s = t; s < TM*64; s += 512) {
    const int row = s >> 6, col = s & 63;
    float v = 0.f;
    if (col < 5)       v = (col == o) ? 1.f : 0.f;
    else if (col < 20) v = initial_s[(bbase+row)*15 + col - 5];
    else if (col < 32) v = initial_c[(bbase+row)*30 + d_OIDS[o][col-20]];
    else if (col < 44) v = current_c[(bbase+row)*30 + d_OIDS[o][col-32]];
    s_in[row*64 + (col ^ ((row & 7) << 3))] = f2b(v);
  }
  __syncthreads();

  layer_mfma<2, 64>  (s_in,  ws + UO_EW0, enc_b0, s_act, s_bs, wave, lane, t);  // h1
  layer_mfma<16, 512>(s_act, ws + UO_EW1, enc_b1, s_act, s_bs, wave, lane, t);  // h2

  // ---- heads: means / log_var / z (waves 0-3 own M-tiles) ----
  {
    // decoder input (non-z cols): [oh 0-4 | z 5-13 | s 14-28 | gi 29-40 | 0]
    for (int s = t; s < TM*64; s += 512) {
      const int row = s >> 6, col = s & 63;
      if (col >= 5 && col < 14) continue;
      float v = 0.f;
      if (col < 5)       v = (col == o) ? 1.f : 0.f;
      else if (col < 29) v = initial_s[(bbase+row)*15 + col - 14];
      else if (col < 41) v = initial_c[(bbase+row)*30 + d_OIDS[o][col-29]];
      s_in[row*64 + (col ^ ((row & 7) << 3))] = f2b(v);
    }
    f32x4 am, av;
    if (wave < 4) {
      const float bmv = (lcol < 9) ? bm[lcol] : 0.f;
      const float bvv = (lcol < 9) ? bv[lcol] : 0.f;
      am = (f32x4){bmv, bmv, bmv, bmv};
      av = (f32x4){bvv, bvv, bvv, bvv};
      const unsigned short* hpM = ws + UO_HEADS + lcol*512 + lk;
      const unsigned short* hpV = hpM + 16*512;
      const int hrow = wave*16 + lcol;
      bf16x8 m0 = *(const bf16x8*)hpM;
      bf16x8 v0 = *(const bf16x8*)hpV;
      #pragma unroll 1
      for (int kt = 0; kt < 16; ++kt) {
        bf16x8 m1 = m0, v1 = v0;
        if (kt + 1 < 16) {                 // register ping-pong prefetch
          m1 = *(const bf16x8*)(hpM + (kt+1)*32);
          v1 = *(const bf16x8*)(hpV + (kt+1)*32);
        }
        const int k0 = kt*32 + lk;
        bf16x8 a = *(const bf16x8*)&s_act[hrow*512 + (k0 ^ ((lcol & 7) << 3))];
        am = __builtin_amdgcn_mfma_f32_16x16x32_bf16(a, m0, am, 0, 0, 0);
        av = __builtin_amdgcn_mfma_f32_16x16x32_bf16(a, v0, av, 0, 0, 0);
        m0 = m1; v0 = v1;
      }
    }
    __syncthreads();   // head reads of s_act done; s_bs free -> stage area
    float* stage = (float*)s_bs;          // [3][64][9] f32 = 6.9 KB
    if (wave < 4 && lcol < 9) {
      #pragma unroll
      for (int r = 0; r < 4; ++r) {
        const int row = wave*16 + rbase + r;
        const int gid = (o*BATCH + bbase + row)*9 + lcol;
        const float m_ = am[r], v_ = av[r];
        const float zz = fmaf(eps[gid], expf(0.5f*v_), m_);
        stage[       row*9 + lcol] = m_;
        stage[576 +  row*9 + lcol] = v_;
        stage[1152 + row*9 + lcol] = zz;
        s_in[row*64 + ((5 + lcol) ^ ((row & 7) << 3))] = f2b(zz);
      }
    }
    __syncthreads();
    // coalesced nontemporal head-output writes (contiguous 2.3 KB each)
    const int ob_m = OUT_MEANS + (o*BATCH + bbase)*9;
    const int ob_v = OUT_LV    + (o*BATCH + bbase)*9;
    const int ob_z = OUT_Z     + (o*BATCH + bbase)*9;
    for (int i = t; i < TM*9; i += 512) {
      __builtin_nontemporal_store(stage[i],        &out[ob_m + i]);
      __builtin_nontemporal_store(stage[576 + i],  &out[ob_v + i]);
      __builtin_nontemporal_store(stage[1152 + i], &out[ob_z + i]);
    }
    __syncthreads();   // stage reads done before dec0 re-stages into s_bs
  }

  layer_mfma<2, 64>  (s_in,  ws + UO_DW0, dec_b0, s_act, s_bs, wave, lane, t);  // g1
  layer_mfma<16, 512>(s_act, ws + UO_DW1, dec_b1, s_act, s_bs, wave, lane, t);  // g2

  // ---- dec head: sigmoid + atomic scatter (exactly 2 commutative adds/elem) ----
  if (wave < 4) {
    const float b2 = (lcol < 12) ? dec_b2[lcol] : 0.f;
    f32x4 acc = (f32x4){b2, b2, b2, b2};
    const unsigned short* wp = ws + UO_DW2 + lcol*512 + lk;
    const int hrow = wave*16 + lcol;
    bf16x8 b0 = *(const bf16x8*)wp;
    #pragma unroll 1
    for (int kt = 0; kt < 16; ++kt) {
      bf16x8 b1 = b0;
      if (kt + 1 < 16) b1 = *(const bf16x8*)(wp + (kt+1)*32);
      const int k0 = kt*32 + lk;
      bf16x8 a = *(const bf16x8*)&s_act[hrow*512 + (k0 ^ ((lcol & 7) << 3))];
      acc = __builtin_amdgcn_mfma_f32_16x16x32_bf16(a, b0, acc, 0, 0, 0);
      b0 = b1;
    }
    if (lcol < 12) {
      const int c30 = d_OIDS[o][lcol];
      #pragma unroll
      for (int r = 0; r < 4; ++r) {
        const int row = wave*16 + rbase + r;
        atomicAdd(&out[(bbase + row)*30 + c30], 1.f / (1.f + expf(-acc[r])));
      }
    }
  }
}

// ---------------- fallback (ws too small): correct but slow fp32 ----------------
__global__ void __launch_bounds__(256)
vae_naive(const float* __restrict__ initial_c, const float* __restrict__ initial_s,
          const float* __restrict__ current_c, const float* __restrict__ eps,
          const float* eW0, const float* eb0, const float* eW1, const float* eb1,
          const float* Wm, const float* bm, const float* Wv, const float* bv,
          const float* dW0, const float* db0, const float* dW1, const float* db1,
          const float* dW2, const float* db2, float* out)
{
  __shared__ float xs[44], ds[41], h1[HID], h2[HID], rec[30];
  const int b = blockIdx.x, t = threadIdx.x;
  if (t < 30) rec[t] = 0.f;
  for (int o = 0; o < NOBJ; ++o) {
    __syncthreads();
    if (t < 44) {
      float v;
      if      (t < 5)  v = (t == o) ? 1.f : 0.f;
      else if (t < 20) v = initial_s[b*15 + (t-5)];
      else if (t < 32) v = initial_c[b*30 + d_OIDS[o][t-20]];
      else             v = current_c[b*30 + d_OIDS[o][t-32]];
      xs[t] = v;
    }
    __syncthreads();
    for (int h = t; h < HID; h += 256) {
      float a = eb0[h];
      for (int k = 0; k < 44; ++k) a = fmaf(xs[k], eW0[h*44+k], a);
      h1[h] = fmaxf(a, 0.f);
    }
    __syncthreads();
    for (int h = t; h < HID; h += 256) {
      float a = eb1[h];
      for (int k = 0; k < HID; ++k) a = fmaf(h1[k], eW1[h*512+k], a);
      h2[h] = fmaxf(a, 0.f);
    }
    __syncthreads();
    if (t < 9) {
      float am = bm[t], av = bv[t];
      for (int k = 0; k < HID; ++k) { am = fmaf(h2[k], Wm[t*512+k], am); av = fmaf(h2[k], Wv[t*512+k], av); }
      const int gid = (o*BATCH + b)*9 + t;
      out[OUT_MEANS + gid] = am;
      out[OUT_LV    + gid] = av;
      const float zz = fmaf(eps[gid], expf(0.5f*av), am);
      out[OUT_Z     + gid] = zz;
      ds[5+t] = zz;
    }
    if (t < 41 && (t < 5 || t >= 14)) {
      float v;
      if      (t < 5)  v = (t == o) ? 1.f : 0.f;
      else if (t < 29) v = initial_s[b*15 + (t-14)];
      else             v = initial_c[b*30 + d_OIDS[o][t-29]];
      ds[t] = v;
    }
    __syncthreads();
    for (int h = t; h < HID; h += 256) {
      float a = db0[h];
      for (int k = 0; k < 41; ++k) a = fmaf(ds[k], dW0[h*41+k], a);
      h1[h] = fmaxf(a, 0.f);
    }
    __syncthreads();
    for (int h = t; h < HID; h += 256) {
      float a = db1[h];
      for (int k = 0; k < HID; ++k) a = fmaf(h1[k], dW1[h*512+k], a);
      h2[h] = fmaxf(a, 0.f);
    }
    __syncthreads();
    if (t < 12) {
      float a = db2[t];
      for (int k = 0; k < HID; ++k) a = fmaf(h2[k], dW2[t*512+k], a);
      rec[d_OIDS[o][t]] += 1.f / (1.f + expf(-a));
    }
  }
  __syncthreads();
  if (t < 30) out[b*30+t] = rec[t];
}

extern "C" void kernel_launch(void* const* d_in, const int* in_sizes, int n_in,
                              void* d_out, int out_size, void* d_ws, size_t ws_size,
                              hipStream_t stream)
{
  const float* initial_c = (const float*)d_in[0];
  const float* initial_s = (const float*)d_in[1];
  const float* current_c = (const float*)d_in[2];
  const float* eps       = (const float*)d_in[3];
  const float* eW0 = (const float*)d_in[4];
  const float* eb0 = (const float*)d_in[5];
  const float* eW1 = (const float*)d_in[6];
  const float* eb1 = (const float*)d_in[7];
  const float* Wm  = (const float*)d_in[8];
  const float* bm  = (const float*)d_in[9];
  const float* Wv  = (const float*)d_in[10];
  const float* bv  = (const float*)d_in[11];
  const float* dW0 = (const float*)d_in[12];
  const float* db0 = (const float*)d_in[13];
  const float* dW1 = (const float*)d_in[14];
  const float* db1 = (const float*)d_in[15];
  const float* dW2 = (const float*)d_in[16];
  const float* db2 = (const float*)d_in[17];
  float* out = (float*)d_out;

  if (ws_size >= (size_t)UO_TOTAL * sizeof(unsigned short)) {
    unsigned short* ws = (unsigned short*)d_ws;
    prep_bf16<<<1024, 256, 0, stream>>>(eW0, eW1, Wm, Wv, dW0, dW1, dW2, ws);
    // zero the reconstructed region (atomics accumulate into it)
    hipMemsetAsync(out, 0, (size_t)BATCH * 30 * sizeof(float), stream);
    vae_mfma<<<NOBJ*NBT, 512, 0, stream>>>(initial_c, initial_s, current_c, eps,
                                           eb0, eb1, bm, bv, db0, db1, db2, ws, out);
  } else {
    vae_naive<<<BATCH, 256, 0, stream>>>(initial_c, initial_s, current_c, eps,
                                         eW0, eb0, eW1, eb1, Wm, bm, Wv, bv,
                                         dW0, db0, dW1, db1, dW2, db2, out);
  }
}